// Round 22
// baseline (57.081 us; speedup 1.0000x reference)
//
#include <hip/hip_runtime.h>

#define NN   4096
#define MM   8191   // 2*NN - 1
#define BB   256
#define CAP  256    // u16 slots per row (nnz/row ~41, max ~70)

__device__ __forceinline__ int prefix_lt(unsigned long long m) {
    return __builtin_amdgcn_mbcnt_hi((unsigned)(m >> 32),
           __builtin_amdgcn_mbcnt_lo((unsigned)m, 0u));
}

// round-to-nearest-even pack of two f32 into 2x bf16 in one uint
__device__ __forceinline__ unsigned pack2bf(float lo, float hi) {
    unsigned a = __float_as_uint(lo);
    unsigned b = __float_as_uint(hi);
    a += 0x7fffu + ((a >> 16) & 1u);
    b += 0x7fffu + ((b >> 16) & 1u);
    return (a >> 16) | (b & 0xffff0000u);
}

// ---------------------------------------------------------------------------
// k_prep: zero part2[256*256]; pack dd = bf16(d1-d2) (2 MB). One uint2/thread.
// (R7's proven prep + part2 zeroing.)
// ---------------------------------------------------------------------------
__global__ __launch_bounds__(256) void k_prep(const float4* __restrict__ d1,
                                              const float4* __restrict__ d2,
                                              float* __restrict__ part2,
                                              uint2* __restrict__ ddp) {
    int idx = blockIdx.x * 256 + threadIdx.x;          // 0..262143
    if (idx < 256 * BB) part2[idx] = 0.0f;
    float4 a = d1[idx], b = d2[idx];
    uint2 r;
    r.x = pack2bf(a.x - b.x, a.y - b.y);
    r.y = pack2bf(a.z - b.z, a.w - b.w);
    ddp[idx] = r;
}

// ---------------------------------------------------------------------------
// k_compact: one wave per ROW — measured AT the 6.2 TB/s stream roofline
// (R7, 21 us). Two sequential 8-load halves; ballot+mbcnt compaction into
// per-wave u16 LDS buffer; direct cnt[m] store; uint4 writeout.
// ---------------------------------------------------------------------------
__global__ __launch_bounds__(256, 4) void k_compact(
        const float4* __restrict__ st4,
        int* __restrict__ cnt,
        unsigned short* __restrict__ list) {
    __shared__ unsigned short s_buf[4][CAP];
    const int wave = threadIdx.x >> 6;
    const int lane = threadIdx.x & 63;
    unsigned short* buf = s_buf[wave];
    const int m = blockIdx.x * 4 + wave;
    if (m >= MM) return;

    int c = 0;
    #pragma unroll
    for (int h = 0; h < 2; ++h) {
        const float4* base = st4 + (size_t)m * (NN / 4) + h * (NN / 8);
        float4 v0 = base[lane];
        float4 v1 = base[64  + lane];
        float4 v2 = base[128 + lane];
        float4 v3 = base[192 + lane];
        float4 v4 = base[256 + lane];
        float4 v5 = base[320 + lane];
        float4 v6 = base[384 + lane];
        float4 v7 = base[448 + lane];

        const int cb = h * (NN / 2);
        #define SITE(val, col)                                          \
        {                                                               \
            unsigned long long mk = __ballot((val) != 0.0f);            \
            if ((val) != 0.0f)                                          \
                buf[c + prefix_lt(mk)] = (unsigned short)(col);         \
            c += __popcll(mk);                                          \
        }
        #define QUAD(v, cb0)                                            \
            SITE(v.x, (cb0))     SITE(v.y, (cb0) + 1)                   \
            SITE(v.z, (cb0) + 2) SITE(v.w, (cb0) + 3)
        QUAD(v0, cb + (lane)       * 4)
        QUAD(v1, cb + (64  + lane) * 4)
        QUAD(v2, cb + (128 + lane) * 4)
        QUAD(v3, cb + (192 + lane) * 4)
        QUAD(v4, cb + (256 + lane) * 4)
        QUAD(v5, cb + (320 + lane) * 4)
        QUAD(v6, cb + (384 + lane) * 4)
        QUAD(v7, cb + (448 + lane) * 4)
        #undef QUAD
        #undef SITE
    }
    __builtin_amdgcn_wave_barrier();   // LDS writes before reads

    if (lane == 0) cnt[m] = c;
    uint4* lv = (uint4*)(list + (size_t)m * CAP);
    const int nv = (c + 7) >> 3;
    if (lane < nv) lv[lane] = ((const uint4*)buf)[lane];
}

// ---------------------------------------------------------------------------
// k_gather: R7's exact 7.05 us/rep geometry — 2048 blocks x 256 thr, one
// wave per row, list preloaded to LDS (8B/lane), 4-deep uint2 bf16 gathers,
// LDS block reduction. Tail: part2[(bid&255)] 8-deep atomic chains (~0.3 us)
// instead of R7's 2048-deep w1sum chain (~60 us — the misattributed cost
// that sent R11-R21 down the fusion path).
// ---------------------------------------------------------------------------
__global__ __launch_bounds__(256, 8) void k_gather(
        const uint2* __restrict__ ddp,
        const int* __restrict__ cnt,
        const unsigned short* __restrict__ list,
        const float* __restrict__ param,
        const int*   __restrict__ parents,
        float* __restrict__ part2) {
    __shared__ unsigned long long s_listq[4][CAP / 4];   // 64 qwords/wave
    __shared__ float s_part[BB];
    const int tid  = threadIdx.x;
    const int wave = tid >> 6;
    const int lane = tid & 63;

    s_part[tid] = 0.0f;
    __syncthreads();

    const int m = blockIdx.x * 4 + wave;
    float r0 = 0.f, r1 = 0.f, r2 = 0.f, r3 = 0.f;
    float wgt = 0.0f;

    if (m < MM) {
        int c = cnt[m];
        if (c > CAP) c = CAP;
        const unsigned long long* lsrc =
            (const unsigned long long*)(list + (size_t)m * CAP);
        s_listq[wave][lane] = lsrc[lane];
        __builtin_amdgcn_wave_barrier();
        wgt = param[parents[m]] - param[m];

        #define UNP0(u) __uint_as_float((u) << 16)
        #define UNP1(u) __uint_as_float((u) & 0xffff0000u)
        float c0 = 0.f, c1 = 0.f, c2 = 0.f, c3 = 0.f;
        float e0 = 0.f, e1 = 0.f, e2 = 0.f, e3 = 0.f;
        int i = 0;
        for (; i + 4 <= c; i += 4) {
            unsigned long long pk = s_listq[wave][i >> 2];
            int n0 = (int)( pk        & 0xffffULL);
            int n1 = (int)((pk >> 16) & 0xffffULL);
            int n2 = (int)((pk >> 32) & 0xffffULL);
            int n3 = (int)((pk >> 48) & 0xffffULL);
            uint2 g0 = ddp[(size_t)n0 * 64 + lane];
            uint2 g1 = ddp[(size_t)n1 * 64 + lane];
            uint2 g2 = ddp[(size_t)n2 * 64 + lane];
            uint2 g3 = ddp[(size_t)n3 * 64 + lane];
            c0 += UNP0(g0.x); c1 += UNP1(g0.x); c2 += UNP0(g0.y); c3 += UNP1(g0.y);
            e0 += UNP0(g1.x); e1 += UNP1(g1.x); e2 += UNP0(g1.y); e3 += UNP1(g1.y);
            c0 += UNP0(g2.x); c1 += UNP1(g2.x); c2 += UNP0(g2.y); c3 += UNP1(g2.y);
            e0 += UNP0(g3.x); e1 += UNP1(g3.x); e2 += UNP0(g3.y); e3 += UNP1(g3.y);
        }
        for (; i < c; ++i) {
            int n = (int)((s_listq[wave][i >> 2] >> ((i & 3) * 16)) & 0xffffULL);
            uint2 g = ddp[(size_t)n * 64 + lane];
            c0 += UNP0(g.x); c1 += UNP1(g.x); c2 += UNP0(g.y); c3 += UNP1(g.y);
        }
        r0 = c0 + e0; r1 = c1 + e1; r2 = c2 + e2; r3 = c3 + e3;
        #undef UNP0
        #undef UNP1
    }

    atomicAdd(&s_part[4 * lane + 0], wgt * fabsf(r0));
    atomicAdd(&s_part[4 * lane + 1], wgt * fabsf(r1));
    atomicAdd(&s_part[4 * lane + 2], wgt * fabsf(r2));
    atomicAdd(&s_part[4 * lane + 3], wgt * fabsf(r3));
    __syncthreads();
    atomicAdd(&part2[(size_t)(blockIdx.x & 255) * BB + tid], s_part[tid]);
}

// ---------------------------------------------------------------------------
// k_finalize: 1024 threads; (sl,b) sums 64 of 256 part2 rows 8-deep; LDS-
// reduce s-slices; out = sum_b (ot[b]-0.5*w1[b])^2.
// ---------------------------------------------------------------------------
__global__ __launch_bounds__(1024) void k_finalize(const float* __restrict__ part2,
                                                   const float* __restrict__ ot,
                                                   float* __restrict__ out) {
    __shared__ float s_red[4][BB];
    __shared__ float s_sq[16];
    const int tid = threadIdx.x;
    const int sl = tid >> 8, b = tid & 255;

    float a0 = 0.f, a1 = 0.f, a2 = 0.f, a3 = 0.f;
    float a4 = 0.f, a5 = 0.f, a6 = 0.f, a7 = 0.f;
    #pragma unroll
    for (int jj = 0; jj < 64; jj += 8) {
        int row = sl * 64 + jj;
        a0 += part2[(row    ) * BB + b];
        a1 += part2[(row + 1) * BB + b];
        a2 += part2[(row + 2) * BB + b];
        a3 += part2[(row + 3) * BB + b];
        a4 += part2[(row + 4) * BB + b];
        a5 += part2[(row + 5) * BB + b];
        a6 += part2[(row + 6) * BB + b];
        a7 += part2[(row + 7) * BB + b];
    }
    s_red[sl][b] = ((a0 + a1) + (a2 + a3)) + ((a4 + a5) + (a6 + a7));
    __syncthreads();

    float v = 0.0f;
    if (sl == 0) {
        float w1 = (s_red[0][b] + s_red[1][b]) + (s_red[2][b] + s_red[3][b]);
        float e = ot[b] - 0.5f * w1;
        v = e * e;
    }
    #pragma unroll
    for (int off = 32; off > 0; off >>= 1) v += __shfl_down(v, off, 64);
    if ((tid & 63) == 0) s_sq[tid >> 6] = v;
    __syncthreads();
    if (tid == 0) out[0] = (s_sq[0] + s_sq[1]) + (s_sq[2] + s_sq[3]);
}

// ---------------------------------------------------------------------------
extern "C" void kernel_launch(void* const* d_in, const int* in_sizes, int n_in,
                              void* d_out, int out_size, void* d_ws, size_t ws_size,
                              hipStream_t stream) {
    const float* d1      = (const float*)d_in[0];
    const float* d2      = (const float*)d_in[1];
    const float* ot      = (const float*)d_in[2];
    const float* subtree = (const float*)d_in[3];
    const float* param   = (const float*)d_in[4];
    const int*   parents = (const int*)d_in[5];

    char* wsb = (char*)d_ws;
    float* part2 = (float*)wsb;                           // 256 KB
    size_t off = 256 * BB * 4;
    uint2* ddp = (uint2*)(wsb + off);                     // 2 MB bf16 dd
    off += (size_t)NN * BB * 2;
    int* cnt = (int*)(wsb + off);                         // 32 KB
    off += ((size_t)MM * 4 + 15) & ~(size_t)15;
    unsigned short* list = (unsigned short*)(wsb + off);  // ~4.2 MB

    k_prep<<<1024, 256, 0, stream>>>((const float4*)d1, (const float4*)d2,
                                     part2, ddp);
    k_compact<<<2048, 256, 0, stream>>>((const float4*)subtree, cnt, list);
    k_gather<<<2048, 256, 0, stream>>>(ddp, cnt, list, param, parents, part2);
    k_finalize<<<1, 1024, 0, stream>>>(part2, ot, (float*)d_out);
}

// Round 23
// 47.330 us; speedup vs baseline: 1.2060x; 1.2060x over previous
//
#include <hip/hip_runtime.h>
#include <hip/hip_fp8.h>

#define NN    4096
#define MM    8191   // 2*NN - 1
#define BB    256
#define CAP   256    // u16 slots per row

typedef float nfloat4 __attribute__((ext_vector_type(4)));
typedef float f32x2 __attribute__((ext_vector_type(2)));

__device__ __forceinline__ int prefix_lt(unsigned long long m) {
    return __builtin_amdgcn_mbcnt_hi((unsigned)(m >> 32),
           __builtin_amdgcn_mbcnt_lo((unsigned)m, 0u));
}

#if defined(__has_builtin)
#if __has_builtin(__builtin_amdgcn_cvt_pk_fp8_f32) && __has_builtin(__builtin_amdgcn_cvt_pk_f32_fp8)
#define HW_FP8 1
#endif
#endif

// pack 4 f32 -> 4x e4m3 in one uint (cols 0..3 = bytes 0..3)
__device__ __forceinline__ unsigned pack4fp8(float x0, float x1, float x2, float x3) {
#ifdef HW_FP8
    int r = 0;
    r = __builtin_amdgcn_cvt_pk_fp8_f32(x0, x1, r, false);  // low word
    r = __builtin_amdgcn_cvt_pk_fp8_f32(x2, x3, r, true);   // high word
    return (unsigned)r;
#else
    __hip_fp8_e4m3 a(x0), b(x1), c(x2), d(x3);
    return (unsigned)a.__x | ((unsigned)b.__x << 8) |
           ((unsigned)c.__x << 16) | ((unsigned)d.__x << 24);
#endif
}

// ---------------------------------------------------------------------------
// k_prep: zero part2; dd8 = fp8_e4m3(d1-d2) (1 MB).
// ---------------------------------------------------------------------------
__global__ __launch_bounds__(256) void k_prep(const float4* __restrict__ d1,
                                              const float4* __restrict__ d2,
                                              float* __restrict__ part2,
                                              unsigned* __restrict__ dd8) {
    int idx = blockIdx.x * 256 + threadIdx.x;          // 0..262143
    if (idx < 256 * BB) part2[idx] = 0.0f;
    float4 a = d1[idx], b = d2[idx];
    dd8[idx] = pack4fp8(a.x - b.x, a.y - b.y, a.z - b.z, a.w - b.w);
}

// ---------------------------------------------------------------------------
// k_fused (best measured, R16, 47.2 us): 2048 blocks x 4 waves, one wave per
// row. Scan row (2 halves x 8 nt float4 — the 6.2 TB/s stream pattern) ->
// ballot+mbcnt compaction into per-wave LDS u16 list -> 8-deep DWORD gathers
// from the 1 MB L2-resident fp8 dd. 22-round ledger: stream (21 us, at HBM
// roofline) and gather (~17 us) costs ADD under every overlap structure
// tried (8 structures) — both consume per-CU vector-memory line slots.
// ---------------------------------------------------------------------------
__global__ __launch_bounds__(256, 4) void k_fused(
        const nfloat4* __restrict__ st4,
        const unsigned* __restrict__ dd8,
        const float* __restrict__ param,
        const int*   __restrict__ parents,
        float* __restrict__ part2) {
    __shared__ unsigned short s_idx[4][CAP];
    __shared__ float s_part[BB];
    const int tid  = threadIdx.x;
    const int wave = tid >> 6;
    const int lane = tid & 63;
    unsigned short* buf = s_idx[wave];

    s_part[tid] = 0.0f;
    __syncthreads();

    const int m = blockIdx.x * 4 + wave;
    if (m < MM) {
        // ---- scan + compact ----------------------------------------------
        int c = 0;
        #pragma unroll
        for (int h = 0; h < 2; ++h) {
            const nfloat4* base = st4 + (size_t)m * (NN / 4) + h * (NN / 8);
            nfloat4 v0 = __builtin_nontemporal_load(base + lane);
            nfloat4 v1 = __builtin_nontemporal_load(base + 64  + lane);
            nfloat4 v2 = __builtin_nontemporal_load(base + 128 + lane);
            nfloat4 v3 = __builtin_nontemporal_load(base + 192 + lane);
            nfloat4 v4 = __builtin_nontemporal_load(base + 256 + lane);
            nfloat4 v5 = __builtin_nontemporal_load(base + 320 + lane);
            nfloat4 v6 = __builtin_nontemporal_load(base + 384 + lane);
            nfloat4 v7 = __builtin_nontemporal_load(base + 448 + lane);

            const int cb = h * (NN / 2);
            #define SITE(val, col)                                          \
            {                                                               \
                unsigned long long mk = __ballot((val) != 0.0f);            \
                if ((val) != 0.0f)                                          \
                    buf[c + prefix_lt(mk)] = (unsigned short)(col);         \
                c += __popcll(mk);                                          \
            }
            #define QUAD(v, cb0)                                            \
                SITE(v.x, (cb0))     SITE(v.y, (cb0) + 1)                   \
                SITE(v.z, (cb0) + 2) SITE(v.w, (cb0) + 3)
            QUAD(v0, cb + (lane)       * 4)
            QUAD(v1, cb + (64  + lane) * 4)
            QUAD(v2, cb + (128 + lane) * 4)
            QUAD(v3, cb + (192 + lane) * 4)
            QUAD(v4, cb + (256 + lane) * 4)
            QUAD(v5, cb + (320 + lane) * 4)
            QUAD(v6, cb + (384 + lane) * 4)
            QUAD(v7, cb + (448 + lane) * 4)
            #undef QUAD
            #undef SITE
        }
        __builtin_amdgcn_wave_barrier();

        // ---- gather (fp8, 8-deep) ----------------------------------------
        float c0 = 0.f, c1 = 0.f, c2 = 0.f, c3 = 0.f;
        float e0 = 0.f, e1 = 0.f, e2 = 0.f, e3 = 0.f;
#ifdef HW_FP8
        #define DEC(u, j0, j1, j2, j3)                                       \
        {                                                                    \
            f32x2 lo = __builtin_amdgcn_cvt_pk_f32_fp8((int)(u), false);     \
            f32x2 hi = __builtin_amdgcn_cvt_pk_f32_fp8((int)(u), true);      \
            j0 += lo.x; j1 += lo.y; j2 += hi.x; j3 += hi.y;                  \
        }
#else
        #define DEC(u, j0, j1, j2, j3)                                       \
        {                                                                    \
            __hip_fp8_e4m3 q0, q1, q2, q3;                                   \
            q0.__x = (unsigned char)(u);                                     \
            q1.__x = (unsigned char)((u) >> 8);                              \
            q2.__x = (unsigned char)((u) >> 16);                             \
            q3.__x = (unsigned char)((u) >> 24);                             \
            j0 += (float)q0; j1 += (float)q1; j2 += (float)q2; j3 += (float)q3; \
        }
#endif
        #define ACCA(u) DEC(u, c0, c1, c2, c3)
        #define ACCB(u) DEC(u, e0, e1, e2, e3)
        const unsigned* lw = (const unsigned*)buf;
        int i = 0;
        for (; i + 8 <= c; i += 8) {
            unsigned q0 = lw[(i >> 1)    ];
            unsigned q1 = lw[(i >> 1) + 1];
            unsigned q2 = lw[(i >> 1) + 2];
            unsigned q3 = lw[(i >> 1) + 3];
            unsigned g0 = dd8[(q0 & 0xffffu) * 64u + lane];
            unsigned g1 = dd8[(q0 >> 16)     * 64u + lane];
            unsigned g2 = dd8[(q1 & 0xffffu) * 64u + lane];
            unsigned g3 = dd8[(q1 >> 16)     * 64u + lane];
            unsigned g4 = dd8[(q2 & 0xffffu) * 64u + lane];
            unsigned g5 = dd8[(q2 >> 16)     * 64u + lane];
            unsigned g6 = dd8[(q3 & 0xffffu) * 64u + lane];
            unsigned g7 = dd8[(q3 >> 16)     * 64u + lane];
            ACCA(g0) ACCB(g1) ACCA(g2) ACCB(g3)
            ACCA(g4) ACCB(g5) ACCA(g6) ACCB(g7)
        }
        for (; i + 4 <= c; i += 4) {
            unsigned q0 = lw[(i >> 1)    ];
            unsigned q1 = lw[(i >> 1) + 1];
            unsigned g0 = dd8[(q0 & 0xffffu) * 64u + lane];
            unsigned g1 = dd8[(q0 >> 16)     * 64u + lane];
            unsigned g2 = dd8[(q1 & 0xffffu) * 64u + lane];
            unsigned g3 = dd8[(q1 >> 16)     * 64u + lane];
            ACCA(g0) ACCB(g1) ACCA(g2) ACCB(g3)
        }
        for (; i < c; ++i) {
            unsigned g = dd8[(unsigned)buf[i] * 64u + lane];
            ACCA(g)
        }
        #undef ACCA
        #undef ACCB
        #undef DEC

        const float wgt = param[parents[m]] - param[m];
        atomicAdd(&s_part[4 * lane + 0], wgt * fabsf(c0 + e0));
        atomicAdd(&s_part[4 * lane + 1], wgt * fabsf(c1 + e1));
        atomicAdd(&s_part[4 * lane + 2], wgt * fabsf(c2 + e2));
        atomicAdd(&s_part[4 * lane + 3], wgt * fabsf(c3 + e3));
    }
    __syncthreads();
    atomicAdd(&part2[(size_t)(blockIdx.x & 255) * BB + tid], s_part[tid]);
}

// ---------------------------------------------------------------------------
// k_finalize: 1024 threads; (s,b) sums 64 of 256 part2 rows 8-deep; LDS-
// reduce s-slices; out = sum_b (ot[b]-0.5*w1[b])^2.
// ---------------------------------------------------------------------------
__global__ __launch_bounds__(1024) void k_finalize(const float* __restrict__ part2,
                                                   const float* __restrict__ ot,
                                                   float* __restrict__ out) {
    __shared__ float s_red[4][BB];
    __shared__ float s_sq[16];
    const int tid = threadIdx.x;
    const int s = tid >> 8, b = tid & 255;

    float a0 = 0.f, a1 = 0.f, a2 = 0.f, a3 = 0.f;
    float a4 = 0.f, a5 = 0.f, a6 = 0.f, a7 = 0.f;
    #pragma unroll
    for (int j = 0; j < 64; j += 8) {
        int row = s * 64 + j;
        a0 += part2[(row    ) * BB + b];
        a1 += part2[(row + 1) * BB + b];
        a2 += part2[(row + 2) * BB + b];
        a3 += part2[(row + 3) * BB + b];
        a4 += part2[(row + 4) * BB + b];
        a5 += part2[(row + 5) * BB + b];
        a6 += part2[(row + 6) * BB + b];
        a7 += part2[(row + 7) * BB + b];
    }
    s_red[s][b] = ((a0 + a1) + (a2 + a3)) + ((a4 + a5) + (a6 + a7));
    __syncthreads();

    float v = 0.0f;
    if (s == 0) {
        float w1 = (s_red[0][b] + s_red[1][b]) + (s_red[2][b] + s_red[3][b]);
        float e = ot[b] - 0.5f * w1;
        v = e * e;
    }
    #pragma unroll
    for (int off = 32; off > 0; off >>= 1) v += __shfl_down(v, off, 64);
    if ((tid & 63) == 0) s_sq[tid >> 6] = v;
    __syncthreads();
    if (tid == 0) out[0] = (s_sq[0] + s_sq[1]) + (s_sq[2] + s_sq[3]);
}

// ---------------------------------------------------------------------------
extern "C" void kernel_launch(void* const* d_in, const int* in_sizes, int n_in,
                              void* d_out, int out_size, void* d_ws, size_t ws_size,
                              hipStream_t stream) {
    const float* d1      = (const float*)d_in[0];
    const float* d2      = (const float*)d_in[1];
    const float* ot      = (const float*)d_in[2];
    const float* subtree = (const float*)d_in[3];
    const float* param   = (const float*)d_in[4];
    const int*   parents = (const int*)d_in[5];

    char* wsb = (char*)d_ws;
    float* part2   = (float*)wsb;                       // 256*256 f = 256 KB
    unsigned* dd8  = (unsigned*)(wsb + 256 * BB * 4);   // 1 MB packed fp8

    k_prep<<<1024, 256, 0, stream>>>((const float4*)d1, (const float4*)d2,
                                     part2, dd8);
    k_fused<<<2048, 256, 0, stream>>>((const nfloat4*)subtree, dd8,
                                      param, parents, part2);
    k_finalize<<<1, 1024, 0, stream>>>(part2, ot, (float*)d_out);
}